// Round 2
// baseline (125.263 us; speedup 1.0000x reference)
//
#include <hip/hip_runtime.h>
#include <hip/hip_bf16.h>

#define NN 4096
#define FF 128
#define HEADS 8
#define UU 8
#define NC 80   // 64 value cols + 8 expEr cols + 1 ones col + 7 pad

typedef __attribute__((ext_vector_type(4))) float float4v;
typedef __attribute__((ext_vector_type(4))) unsigned int uint4v;
typedef __attribute__((ext_vector_type(8))) short short8;

// ---------------------------------------------------------------------------
// Kernel 1: per node j compute HW[h,j,u] = sum_f H[j,f] W[h,f,u],
// e_l/e_r reductions, and write B_pack (bf16) in MFMA B-fragment layout:
//   element (k=j, c) lives at Bp[((j>>5)*4 + ((j>>3)&3))*NC + c] * 8 + (j&7)
// cols: c in [0,64): expEr[h]*HW[h,j,u] (c=h*8+u); c in [64,72): expEr[h];
//       c==72: 1.0 (degree column); c in (72,80): 0.
// Also store expEl[h*N + j] (f32).
// ---------------------------------------------------------------------------
__global__ __launch_bounds__(64) void gat_prep(const float* __restrict__ H,
                                               const float* __restrict__ W,
                                               const float* __restrict__ al,
                                               const float* __restrict__ ar,
                                               float* __restrict__ expEl,
                                               __hip_bfloat16* __restrict__ Bp)
{
    const int j = blockIdx.x;
    const int t = threadIdx.x;       // 0..63
    const int h = t >> 3, u = t & 7;

    __shared__ float hrow[FF];
    for (int f = t; f < FF; f += 64) hrow[f] = H[j * FF + f];
    __syncthreads();

    // HW[h][j][u]
    float acc = 0.f;
    const float* Wp = W + (size_t)h * FF * UU + u;   // W[h][f][u]
    #pragma unroll 4
    for (int f = 0; f < FF; ++f) acc += hrow[f] * Wp[(size_t)f * UU];

    float vr = acc * ar[h * UU + u];
    float vl = acc * al[h * UU + u];
    // reduce over u within each 8-lane group
    #pragma unroll
    for (int s = 1; s < 8; s <<= 1) { vr += __shfl_xor(vr, s); vl += __shfl_xor(vl, s); }
    const float er = expf(vr);          // exp(e_r[h,j]) on all lanes of group h
    const float el = expf(vl);          // exp(e_l[h,j])
    if (u == 0) expEl[h * NN + j] = el;

    // broadcast expEr[h'] for h' = t&7 (sources are lanes 0,8,...,56 — all active)
    const float er_b = __shfl(er, (t & 7) * 8);

    const int kt = j >> 5, q = (j >> 3) & 3, j8 = j & 7;
    const size_t base = ((size_t)(kt * 4 + q) * NC) * 8 + j8;
    Bp[base + (size_t)(h * 8 + u) * 8] = __float2bfloat16(er * acc);

    if (t < 16) {
        const int c = 64 + t;
        float v;
        if (t < 8)       v = er_b;      // expEr column (for S)
        else if (t == 8) v = 1.0f;      // degree column
        else             v = 0.0f;      // pad
        Bp[base + (size_t)c * 8] = __float2bfloat16(v);
    }
}

// ---------------------------------------------------------------------------
// Kernel 2: C[i,c] = sum_j A[i,j] * B[j,c], M=4096, N=80, K=4096.
// A is f32 0/1 -> truncate to bf16 in-register (exact). MFMA 16x16x32 bf16.
// grid = (64 row-blocks, KC k-chunks); block = 256 (4 waves, 16 rows each).
// Partials to Cp[kc][row][NC] f32.
// ---------------------------------------------------------------------------
__global__ __launch_bounds__(256) void gat_gemm(const float* __restrict__ A,
                                                const __hip_bfloat16* __restrict__ Bp,
                                                float* __restrict__ Cp,
                                                int ktiles)
{
    const int rb   = blockIdx.x;            // 0..63
    const int kc   = blockIdx.y;            // 0..KC-1
    const int wave = threadIdx.x >> 6;
    const int lane = threadIdx.x & 63;
    const int m16  = lane & 15;
    const int q    = lane >> 4;
    const int row0 = rb * 64 + wave * 16;

    float4v acc[5] = {};

    const int k0 = kc * (ktiles * 32);
    const unsigned int* Au = (const unsigned int*)A;
    const short* Bs = (const short*)Bp;

    for (int kt = 0; kt < ktiles; ++kt) {
        const int kk = k0 + kt * 32;
        // A fragment: A[row0+m16][kk + q*8 .. +8) as f32, pack high halves -> bf16
        const unsigned int* arow = Au + (size_t)(row0 + m16) * NN + kk + q * 8;
        uint4v a0 = *(const uint4v*)arow;
        uint4v a1 = *(const uint4v*)(arow + 4);
        short8 afrag;
        afrag[0] = (short)(a0[0] >> 16); afrag[1] = (short)(a0[1] >> 16);
        afrag[2] = (short)(a0[2] >> 16); afrag[3] = (short)(a0[3] >> 16);
        afrag[4] = (short)(a1[0] >> 16); afrag[5] = (short)(a1[1] >> 16);
        afrag[6] = (short)(a1[2] >> 16); afrag[7] = (short)(a1[3] >> 16);

        const int ktg = kk >> 5;
        const short8* bbase = (const short8*)(Bs + ((size_t)(ktg * 4 + q) * NC) * 8);
        #pragma unroll
        for (int nt = 0; nt < 5; ++nt) {
            short8 bfrag = bbase[nt * 16 + m16];
            acc[nt] = __builtin_amdgcn_mfma_f32_16x16x32_bf16(afrag, bfrag, acc[nt], 0, 0, 0);
        }
    }

    float* cbase = Cp + (size_t)kc * NN * NC;
    #pragma unroll
    for (int nt = 0; nt < 5; ++nt) {
        #pragma unroll
        for (int r = 0; r < 4; ++r) {
            const int row = row0 + q * 4 + r;    // C/D: col=lane&15, row=(lane>>4)*4+reg
            const int col = nt * 16 + m16;
            cbase[(size_t)row * NC + col] = acc[nt][r];
        }
    }
}

// ---------------------------------------------------------------------------
// Kernel 3: reduce KC K-partials, build denom, apply scale + elu, write f32.
// ---------------------------------------------------------------------------
__global__ __launch_bounds__(256) void gat_epilogue(const float* __restrict__ Cp,
                                                    const float* __restrict__ expEl,
                                                    float* __restrict__ out,
                                                    int KC)
{
    const int idx = blockIdx.x * 256 + threadIdx.x;  // [0, 4096*64)
    const int i = idx >> 6;
    const int c = idx & 63;            // h*8+u
    const int h = c >> 3;

    float T = 0.f, S = 0.f, dg = 0.f;
    for (int kc = 0; kc < KC; ++kc) {
        const float* row = Cp + ((size_t)kc * NN + i) * NC;
        T  += row[c];
        S  += row[64 + h];
        dg += row[72];
    }
    const float el = expEl[h * NN + i];
    const float denom = ((float)NN - dg) + el * S;
    const float x = el * T / denom;
    const float y = x > 0.f ? x : expf(x) - 1.f;
    out[idx] = y;
}

extern "C" void kernel_launch(void* const* d_in, const int* in_sizes, int n_in,
                              void* d_out, int out_size, void* d_ws, size_t ws_size,
                              hipStream_t stream) {
    const float* A  = (const float*)d_in[0];
    const float* H  = (const float*)d_in[1];
    const float* W  = (const float*)d_in[2];
    const float* al = (const float*)d_in[3];
    const float* ar = (const float*)d_in[4];
    float* out = (float*)d_out;

    // workspace layout
    float* expEl = (float*)d_ws;                                   // 8*4096 f32 = 128 KB
    __hip_bfloat16* Bp = (__hip_bfloat16*)((char*)d_ws + 131072);  // 128*4*80*8 bf16 = 640 KB
    float* Cp = (float*)((char*)d_ws + 131072 + 655360);           // KC*4096*80 f32

    const size_t fixed = 131072 + 655360;
    int KC = 8;
    while (KC > 1 && fixed + (size_t)KC * NN * NC * 4 > ws_size) KC >>= 1;
    const int ktiles = NN / (KC * 32);

    gat_prep<<<NN, 64, 0, stream>>>(H, W, al, ar, expEl, Bp);
    gat_gemm<<<dim3(NN / 64, KC), 256, 0, stream>>>(A, Bp, Cp, ktiles);
    gat_epilogue<<<NN * 64 / 256, 256, 0, stream>>>(Cp, expEl, out, KC);
}